// Round 9
// baseline (301.037 us; speedup 1.0000x reference)
//
#include <hip/hip_runtime.h>
#include <stdint.h>

#define THRESH 0.5f
#define PSI 0.1f

typedef short bfrag_t __attribute__((ext_vector_type(8)));     // 8 bf16 = 4 VGPRs (MFMA A/B frag)
typedef float f32x16 __attribute__((ext_vector_type(16)));     // 32x32 MFMA C/D frag
typedef unsigned short u16x8 __attribute__((ext_vector_type(8)));

// async global->LDS, 16B per lane, wave-uniform LDS base + lane*16
#define GLD16(gsrc, ldst)                                                                \
    __builtin_amdgcn_global_load_lds((const __attribute__((address_space(1))) void*)(gsrc), \
                                     (__attribute__((address_space(3))) void*)(ldst),       \
                                     16, 0, 0)

#define WAITVM(n)   asm volatile("s_waitcnt vmcnt(" #n ")" ::: "memory")
#define WAITLGKM(n) asm volatile("s_waitcnt lgkmcnt(" #n ")" ::: "memory")
#define SB()        __builtin_amdgcn_sched_barrier(0)
#define BAR()                                  \
    do {                                       \
        asm volatile("" ::: "memory");         \
        __builtin_amdgcn_s_barrier();          \
        asm volatile("" ::: "memory");         \
    } while (0)

__device__ __forceinline__ float dequant(float v) {
    if (v > THRESH) return 1.0f;
    if (v < -THRESH) return -1.0f;
    if (fabsf(v) < PSI) return 0.0f;
    return (v + THRESH) / (2.0f * THRESH);
}

__device__ __forceinline__ unsigned short f2bf(float f) {
    unsigned int u = __float_as_uint(f);
    u += 0x7FFFu + ((u >> 16) & 1u);
    return (unsigned short)(u >> 16);
}

// ---------------------------------------------------------------------------
// Packing kernels: fp32 row-major [R][K] -> bf16 chunk-linear:
//   granule (r, S, hi) = 8 elems src[r][16S+8hi .. +7]
//   packed elem offset = ((r/32)*(K/16) + S)*512 + (hi*32 + (r&31))*8
// ---------------------------------------------------------------------------
template <bool DO_DEQUANT>
__global__ void pack_kernel(const float* __restrict__ src, unsigned short* __restrict__ dst, int K) {
    __shared__ char lsm[16384];
    const int t   = threadIdx.x;       // 0..255
    const int nkc = K >> 8;            // K/256
    const int b   = blockIdx.x / nkc;  // 32-row band
    const int kc  = blockIdx.x % nkc;
    const int k0  = kc << 8;
    const int r   = t >> 3;            // 0..31 row within band
    const int j   = t & 7;             // 0..7  32-float group

    const float4* s4 = (const float4*)(src + (size_t)((b << 5) + r) * K + k0 + (j << 5));
    float4 f[8];
#pragma unroll
    for (int i = 0; i < 8; ++i) f[i] = s4[i];

#pragma unroll
    for (int gi = 0; gi < 4; ++gi) {
        float4 lo = f[2 * gi], hi4 = f[2 * gi + 1];
        u16x8 o;
        if (DO_DEQUANT) {
            o[0] = f2bf(dequant(lo.x));  o[1] = f2bf(dequant(lo.y));
            o[2] = f2bf(dequant(lo.z));  o[3] = f2bf(dequant(lo.w));
            o[4] = f2bf(dequant(hi4.x)); o[5] = f2bf(dequant(hi4.y));
            o[6] = f2bf(dequant(hi4.z)); o[7] = f2bf(dequant(hi4.w));
        } else {
            o[0] = f2bf(lo.x);  o[1] = f2bf(lo.y);  o[2] = f2bf(lo.z);  o[3] = f2bf(lo.w);
            o[4] = f2bf(hi4.x); o[5] = f2bf(hi4.y); o[6] = f2bf(hi4.z); o[7] = f2bf(hi4.w);
        }
        const int S_rel = 2 * j + (gi >> 1);
        const int slot  = ((gi & 1) << 5) + r;
        *(u16x8*)(lsm + S_rel * 1024 + slot * 16) = o;
    }
    __syncthreads();

    unsigned short* gdst = dst + (((size_t)b * (K >> 4) + (kc << 4)) << 9) + (size_t)t * 32;
#pragma unroll
    for (int i = 0; i < 4; ++i)
        *(u16x8*)(gdst + i * 8) = *(const u16x8*)(lsm + t * 64 + i * 16);
}

// ---------------------------------------------------------------------------
// 256x256 bf16 GEMM, 32x32x16 MFMA, counted-lgkmcnt intra-tile pipeline.
// C[M,N] = A[M,K] * B[N,K]^T + bias, fp32 out.
// 8 waves (2Mx4N), per-wave 128x64 = 4x2 frags of 32x32, K=64 per tile.
// LDS 128 KiB = 2 bufs x {A-kh0, A-kh1, B-kh0, B-kh1} x 16 KiB chunk-linear.
// Per tile, 2 barriers:
//  R1: issue 12 ds_reads (A-quad0 mi0-1 + B nn0) | 4 (B nn1) | stage Y.A(t+1);
//      lgkm(4) -> q00 (8 MFMA) overlaps B1 drain;
//      lgkm(0) -> q01 overlaps A-quad1 (mi2-3) read issue;  mid-BAR
//      (every wave drained its B reads at its lgkm(0) -> X.B overwritable)
//  R2: stage X.B(t+2); lgkm(0) -> q11,q10; vmcnt(4) (drains Y.A+Y.B, leaves
//      X.B in flight); final BAR publishes Y.
// sched_barrier(0) pins read-group order and fences MFMA after lgkm waits
// (rule 18). All ds_reads lane-linear: zero bank conflicts.
// ---------------------------------------------------------------------------

__device__ __forceinline__ bfrag_t rdfrag32(const char* halfBase, int band, int ks, int l16) {
    return *(const bfrag_t*)(halfBase + (band << 11) + (ks << 10) + l16);
}

__global__ __launch_bounds__(512, 2) void gemm256p_kernel(
        const unsigned short* __restrict__ Ap,  // M x K, packed chunk-linear
        const unsigned short* __restrict__ Bp,  // N x K, packed chunk-linear
        const float* __restrict__ bias,         // N
        float* __restrict__ C,                  // M x N
        int M, int N, int K) {
    __shared__ char ldsB[131072];   // 2 bufs x {A0:0, A1:16K, B0:32K, B1:48K}

    const int t    = threadIdx.x;
    const int w    = t >> 6;        // wave 0..7
    const int l    = t & 63;
    const int wr   = w >> 2;        // 0..1  (128-row band)
    const int wc   = w & 3;         // 0..3  (64-col band)
    const int lr32 = l & 31;
    const int hi   = l >> 5;
    const int l16  = l << 4;

    // XCD-aware block swizzle (bijective when nwg % 8 == 0)
    const int nwg = gridDim.x;
    int bid = blockIdx.x;
    if ((nwg & 7) == 0) bid = (bid & 7) * (nwg >> 3) + (bid >> 3);
    const int nbn  = N >> 8;
    const int brow = (bid / nbn) << 8;
    const int bcol = (bid % nbn) << 8;

    // packed staging bases: wave w covers 16B granules of chunks c16 = w*2+{0,1}
    const int Kc = K >> 4;          // S-chunks per row-band
    const char* pA = (const char*)Ap + (((size_t)(((brow >> 5) + w) * (size_t)Kc)) << 10) + l16;
    const char* pB = (const char*)Bp + (((size_t)(((bcol >> 5) + w) * (size_t)Kc)) << 10) + l16;
    const int c16a = w * 2 + 0, c16b = w * 2 + 1;

    // LDS half-tile bases (bytes): buf*65536 + {A0:0, A1:16384, B0:32768, B1:49152}
#define STAGE_A(buf, half, kE)                                                              \
    do {                                                                                    \
        const size_t so_ = ((size_t)(((kE) >> 4) + (half) * 2)) << 10;                      \
        GLD16(pA + so_,        ldsB + (buf) * 65536 + (half) * 16384 + c16a * 1024);        \
        GLD16(pA + so_ + 1024, ldsB + (buf) * 65536 + (half) * 16384 + c16b * 1024);        \
    } while (0)
#define STAGE_B(buf, half, kE)                                                              \
    do {                                                                                    \
        const size_t so_ = ((size_t)(((kE) >> 4) + (half) * 2)) << 10;                      \
        GLD16(pB + so_,        ldsB + (buf) * 65536 + 32768 + (half) * 16384 + c16a * 1024);\
        GLD16(pB + so_ + 1024, ldsB + (buf) * 65536 + 32768 + (half) * 16384 + c16b * 1024);\
    } while (0)

    // 8 MFMA: quad qm (mi pair) x col nn over ks 0..3, accumulating
#define QMFMA(qm, bq, nn)                                                                 \
    do {                                                                                  \
        __builtin_amdgcn_s_setprio(1);                                                    \
        _Pragma("unroll") for (int ks = 0; ks < 4; ++ks)                                  \
        _Pragma("unroll") for (int mi = 0; mi < 2; ++mi)                                  \
            acc[(qm) * 2 + mi][nn] = __builtin_amdgcn_mfma_f32_32x32x16_bf16(             \
                a[mi][ks], bq[ks], acc[(qm) * 2 + mi][nn], 0, 0, 0);                      \
        __builtin_amdgcn_s_setprio(0);                                                    \
    } while (0)

    f32x16 acc[4][2];
#pragma unroll
    for (int m = 0; m < 4; ++m)
#pragma unroll
        for (int n = 0; n < 2; ++n)
#pragma unroll
            for (int r = 0; r < 16; ++r)
                acc[m][n][r] = 0.f;

    const int NT = K >> 6;          // BK=64 tiles; NT even, >= 4
    const int wrB4 = wr << 2;       // A band base (bands of 32 rows)
    const int wcB2 = wc << 1;       // B band base

    // ---- prologue: PING(t0) A+B fully, PONG(t1) B halves ----
    STAGE_A(0, 0, 0);  STAGE_A(0, 1, 0);
    STAGE_B(0, 0, 0);  STAGE_B(0, 1, 0);
    STAGE_B(1, 0, 64); STAGE_B(1, 1, 64);
    WAITVM(4);      // PING complete; PONG.B (4) in flight
    BAR();

    bfrag_t a[2][4], b0[4], b1[4];

#define TILE(tv, XO, YO, Xb, Yb)                                                          \
    do {                                                                                  \
        int t1_ = (tv) + 1; if (t1_ >= NT) t1_ -= NT;  /* wrapped: harmless */            \
        int t2_ = (tv) + 2; if (t2_ >= NT) t2_ -= NT;                                     \
        const char* aH0 = ldsB + (XO);                                                    \
        const char* aH1 = aH0 + 16384;                                                    \
        const char* bH0 = aH0 + 32768;                                                    \
        const char* bH1 = aH0 + 49152;                                                    \
        const int kY1 = t1_ << 6, kX2 = t2_ << 6;                                         \
        /* R1: group1 = A-quad0 (8) + B nn0 (4) */                                        \
        _Pragma("unroll") for (int mi = 0; mi < 2; ++mi)                                  \
        _Pragma("unroll") for (int ks = 0; ks < 4; ++ks)                                  \
            a[mi][ks] = rdfrag32(ks < 2 ? aH0 : aH1, wrB4 + mi, ks & 1, l16);             \
        _Pragma("unroll") for (int ks = 0; ks < 4; ++ks)                                  \
            b0[ks] = rdfrag32(ks < 2 ? bH0 : bH1, wcB2 + 0, ks & 1, l16);                 \
        SB();                                                                             \
        /* group2 = B nn1 (4) */                                                          \
        _Pragma("unroll") for (int ks = 0; ks < 4; ++ks)                                  \
            b1[ks] = rdfrag32(ks < 2 ? bH0 : bH1, wcB2 + 1, ks & 1, l16);                 \
        SB();                                                                             \
        STAGE_A(Yb, 0, kY1); STAGE_A(Yb, 1, kY1);                                         \
        WAITLGKM(4); SB();    /* group1 done; b1 may be in flight */                      \
        QMFMA(0, b0, 0);                                                                  \
        WAITLGKM(0); SB();    /* b1 done */                                               \
        QMFMA(0, b1, 1);                                                                  \
        /* A-quad1 (mi 2-3) reads; WAR on 'a' sequenced after q01 */                      \
        _Pragma("unroll") for (int mi = 0; mi < 2; ++mi)                                  \
        _Pragma("unroll") for (int ks = 0; ks < 4; ++ks)                                  \
            a[mi][ks] = rdfrag32(ks < 2 ? aH0 : aH1, wrB4 + 2 + mi, ks & 1, l16);         \
        SB();                                                                             \
        BAR();                /* all waves' B reads drained -> X.B overwritable */        \
        STAGE_B(Xb, 0, kX2); STAGE_B(Xb, 1, kX2);                                         \
        WAITLGKM(0); SB();    /* A-quad1 done */                                          \
        QMFMA(1, b1, 1);                                                                  \
        QMFMA(1, b0, 0);                                                                  \
        WAITVM(4);            /* drains Y.A + Y.B; leaves X.B in flight */                \
        BAR();                /* publish Y */                                             \
    } while (0)

    for (int tt = 0; tt < NT; tt += 2) {
        TILE(tt,     0,     65536, 0, 1);
        TILE(tt + 1, 65536, 0,     1, 0);
    }

    WAITVM(0);      // drain pending LDS writes before wave retires

    // ---- epilogue: 32x32 C/D layout col=lane&31, row=(reg&3)+8*(reg>>2)+4*(lane>>5) ----
    float bv[2];
#pragma unroll
    for (int nn = 0; nn < 2; ++nn) bv[nn] = bias[bcol + (wc << 6) + nn * 32 + lr32];
#pragma unroll
    for (int mm = 0; mm < 4; ++mm) {
#pragma unroll
        for (int nn = 0; nn < 2; ++nn) {
            const int gc = bcol + (wc << 6) + nn * 32 + lr32;
#pragma unroll
            for (int reg = 0; reg < 16; ++reg) {
                const int row = (reg & 3) + 8 * (reg >> 2) + 4 * hi;
                C[(size_t)(brow + (wr << 7) + mm * 32 + row) * N + gc] = acc[mm][nn][reg] + bv[nn];
            }
        }
    }
    (void)M;
#undef STAGE_A
#undef STAGE_B
#undef QMFMA
#undef TILE
}

// ---------------------------------------------------------------------------
// Fallback: fp32 tiled GEMM with on-the-fly dequant (any shape, slow).
// ---------------------------------------------------------------------------
__global__ void gemm_fallback_kernel(const float* __restrict__ X, const float* __restrict__ W,
                                     const float* __restrict__ bias, float* __restrict__ C,
                                     int M, int N, int K) {
    __shared__ float sX[16][17];
    __shared__ float sW[16][17];
    const int tx = threadIdx.x & 15;
    const int ty = threadIdx.x >> 4;
    const int row = blockIdx.y * 16 + ty;
    const int colBase = blockIdx.x * 16;
    const int col = colBase + tx;
    float acc = 0.f;
    for (int k0 = 0; k0 < K; k0 += 16) {
        sX[ty][tx] = (row < M && k0 + tx < K) ? X[(size_t)row * K + k0 + tx] : 0.f;
        const int wrow = colBase + ty;
        sW[ty][tx] = (wrow < N && k0 + tx < K) ? dequant(W[(size_t)wrow * K + k0 + tx]) : 0.f;
        __syncthreads();
#pragma unroll
        for (int kk = 0; kk < 16; ++kk)
            acc += sX[ty][kk] * sW[tx][kk];
        __syncthreads();
    }
    if (row < M && col < N)
        C[(size_t)row * N + col] = acc + bias[col];
}

extern "C" void kernel_launch(void* const* d_in, const int* in_sizes, int n_in,
                              void* d_out, int out_size, void* d_ws, size_t ws_size,
                              hipStream_t stream) {
    const float* x    = (const float*)d_in[0];
    const float* w    = (const float*)d_in[1];
    const float* bias = (const float*)d_in[2];
    float* out        = (float*)d_out;

    const int N = in_sizes[2];
    const int K = in_sizes[1] / N;
    const int M = in_sizes[0] / K;

    const size_t need = ((size_t)M * K + (size_t)N * K) * sizeof(unsigned short);
    const bool fast = (ws_size >= need) && (M % 256 == 0) && (N % 256 == 0) &&
                      (K % 256 == 0);

    if (fast) {
        unsigned short* xp = (unsigned short*)d_ws;
        unsigned short* wp = xp + (size_t)M * K;
        pack_kernel<false><<<dim3((M / 32) * (K / 256)), dim3(256), 0, stream>>>(x, xp, K);
        pack_kernel<true ><<<dim3((N / 32) * (K / 256)), dim3(256), 0, stream>>>(w, wp, K);
        gemm256p_kernel<<<dim3((M / 256) * (N / 256)), dim3(512), 0, stream>>>(xp, wp, bias, out, M, N, K);
    } else {
        dim3 g((N + 15) / 16, (M + 15) / 16);
        gemm_fallback_kernel<<<g, dim3(256), 0, stream>>>(x, w, bias, out, M, N, K);
    }
    (void)n_in; (void)out_size;
}

// Round 10
// 300.419 us; speedup vs baseline: 1.0021x; 1.0021x over previous
//
#include <hip/hip_runtime.h>
#include <stdint.h>

#define THRESH 0.5f
#define PSI 0.1f

typedef short bfrag_t __attribute__((ext_vector_type(8)));     // 8 bf16 = 4 VGPRs (MFMA A/B frag)
typedef float f32x16 __attribute__((ext_vector_type(16)));     // 32x32 MFMA C/D frag
typedef unsigned short u16x8 __attribute__((ext_vector_type(8)));

// async global->LDS, 16B per lane, wave-uniform LDS base + lane*16
#define GLD16(gsrc, ldst)                                                                \
    __builtin_amdgcn_global_load_lds((const __attribute__((address_space(1))) void*)(gsrc), \
                                     (__attribute__((address_space(3))) void*)(ldst),       \
                                     16, 0, 0)

#define WAITVM(n)   asm volatile("s_waitcnt vmcnt(" #n ")" ::: "memory")
#define WAITLGKM(n) asm volatile("s_waitcnt lgkmcnt(" #n ")" ::: "memory")
#define SB()        __builtin_amdgcn_sched_barrier(0)
#define BAR()                                  \
    do {                                       \
        asm volatile("" ::: "memory");         \
        __builtin_amdgcn_s_barrier();          \
        asm volatile("" ::: "memory");         \
    } while (0)

__device__ __forceinline__ float dequant(float v) {
    if (v > THRESH) return 1.0f;
    if (v < -THRESH) return -1.0f;
    if (fabsf(v) < PSI) return 0.0f;
    return (v + THRESH) / (2.0f * THRESH);
}

__device__ __forceinline__ unsigned short f2bf(float f) {
    unsigned int u = __float_as_uint(f);
    u += 0x7FFFu + ((u >> 16) & 1u);
    return (unsigned short)(u >> 16);
}

// ---------------------------------------------------------------------------
// Packing kernels: fp32 row-major [R][K] -> bf16 chunk-linear:
//   granule (r, S, hi) = 8 elems src[r][16S+8hi .. +7]
//   packed elem offset = ((r/32)*(K/16) + S)*512 + (hi*32 + (r&31))*8
// ---------------------------------------------------------------------------
template <bool DO_DEQUANT>
__global__ void pack_kernel(const float* __restrict__ src, unsigned short* __restrict__ dst, int K) {
    __shared__ char lsm[16384];
    const int t   = threadIdx.x;       // 0..255
    const int nkc = K >> 8;            // K/256
    const int b   = blockIdx.x / nkc;  // 32-row band
    const int kc  = blockIdx.x % nkc;
    const int k0  = kc << 8;
    const int r   = t >> 3;            // 0..31 row within band
    const int j   = t & 7;             // 0..7  32-float group

    const float4* s4 = (const float4*)(src + (size_t)((b << 5) + r) * K + k0 + (j << 5));
    float4 f[8];
#pragma unroll
    for (int i = 0; i < 8; ++i) f[i] = s4[i];

#pragma unroll
    for (int gi = 0; gi < 4; ++gi) {
        float4 lo = f[2 * gi], hi4 = f[2 * gi + 1];
        u16x8 o;
        if (DO_DEQUANT) {
            o[0] = f2bf(dequant(lo.x));  o[1] = f2bf(dequant(lo.y));
            o[2] = f2bf(dequant(lo.z));  o[3] = f2bf(dequant(lo.w));
            o[4] = f2bf(dequant(hi4.x)); o[5] = f2bf(dequant(hi4.y));
            o[6] = f2bf(dequant(hi4.z)); o[7] = f2bf(dequant(hi4.w));
        } else {
            o[0] = f2bf(lo.x);  o[1] = f2bf(lo.y);  o[2] = f2bf(lo.z);  o[3] = f2bf(lo.w);
            o[4] = f2bf(hi4.x); o[5] = f2bf(hi4.y); o[6] = f2bf(hi4.z); o[7] = f2bf(hi4.w);
        }
        const int S_rel = 2 * j + (gi >> 1);
        const int slot  = ((gi & 1) << 5) + r;
        *(u16x8*)(lsm + S_rel * 1024 + slot * 16) = o;
    }
    __syncthreads();

    unsigned short* gdst = dst + (((size_t)b * (K >> 4) + (kc << 4)) << 9) + (size_t)t * 32;
#pragma unroll
    for (int i = 0; i < 4; ++i)
        *(u16x8*)(gdst + i * 8) = *(const u16x8*)(lsm + t * 64 + i * 16);
}

// ---------------------------------------------------------------------------
// 256x256 bf16 GEMM, 32x32x16 MFMA. A via LDS, B via register prefetch.
// C[M,N] = A[M,K] * B[N,K]^T + bias, fp32 out.
// 8 waves (2Mx4N), per-wave 128x64 output = 4x2 frags of 32x32; acc in AGPR.
// LDS 64 KiB = 2 bufs x A-tile 32 KiB (chunk-linear, halves of 16 chunks).
// B: packed layout makes a B-frag a lane-linear 1KB global load -> each wave
// loads its 8 B-frags/tile straight to VGPRs, double-buffered (U/V).
// Per tile (2 barriers): read A in 4 ks-groups with counted lgkm(4) so each
// group drains under the previous group's 8 MFMAs; BAR1 after lgkm(0) frees
// buf X; stage A(t+2)->X; MFMA ks3; vmcnt(4) (drains A(t+1)+B(t+1), leaves
// A(t+2)); BAR2 publishes A(t+1). All LDS reads lane-linear: 0 conflicts.
// ---------------------------------------------------------------------------

__global__ __launch_bounds__(512, 2) void gemm256r_kernel(
        const unsigned short* __restrict__ Ap,  // M x K, packed chunk-linear
        const unsigned short* __restrict__ Bp,  // N x K, packed chunk-linear
        const float* __restrict__ bias,         // N
        float* __restrict__ C,                  // M x N
        int M, int N, int K) {
    __shared__ char ldsB[65536];    // 2 bufs x {A-kh0 16K, A-kh1 16K}

    const int t    = threadIdx.x;
    const int w    = t >> 6;        // wave 0..7
    const int l    = t & 63;
    const int wr   = w >> 2;        // 0..1  (128-row band)
    const int wc   = w & 3;         // 0..3  (64-col band)
    const int lr32 = l & 31;
    const int hi   = l >> 5;
    const int l16  = l << 4;

    // XCD-aware block swizzle (bijective when nwg % 8 == 0)
    const int nwg = gridDim.x;
    int bid = blockIdx.x;
    if ((nwg & 7) == 0) bid = (bid & 7) * (nwg >> 3) + (bid >> 3);
    const int nbn  = N >> 8;
    const int brow = (bid / nbn) << 8;
    const int bcol = (bid % nbn) << 8;

    const int Kc = K >> 4;          // S-chunks per row-band
    // A staging: wave w stages row-band w (chunks 2w, 2w+1 of each half)
    const char* pA  = (const char*)Ap + ((((size_t)((brow >> 5) + w)) * Kc) << 10) + l16;
    // B frags: this wave's two col-bands
    const char* pB0 = (const char*)Bp + ((((size_t)((bcol >> 5) + (wc << 1))) * Kc) << 10) + l16;
    const char* pB1 = pB0 + ((size_t)Kc << 10);
    const int c16a = w * 2, c16b = w * 2 + 1;

    // stage A tile tv into buffer at byte offset bufO (4 x 1KB bursts)
#define STAGE_A4(bufO, tv)                                                     \
    do {                                                                       \
        const size_t s0_ = ((size_t)(tv) << 12);                               \
        GLD16(pA + s0_,        ldsB + (bufO) + c16a * 1024);                   \
        GLD16(pA + s0_ + 1024, ldsB + (bufO) + c16b * 1024);                   \
        GLD16(pA + s0_ + 2048, ldsB + (bufO) + 16384 + c16a * 1024);           \
        GLD16(pA + s0_ + 3072, ldsB + (bufO) + 16384 + c16b * 1024);           \
    } while (0)

    // A frag (row-band wr*4+mi, K-slice ksa 0..3) from buf at XO: lane-linear
#define RDA(XO, mi, ksa)                                                       \
    (*(const bfrag_t*)(ldsB + (XO) + (((ksa) >> 1) << 14) +                    \
                       (((wr << 2) + (mi)) << 11) + (((ksa) & 1) << 10) + l16))

    // load B frags of tile tb into Vv (8 x dwordx4, coalesced 1KB each)
#define LDB(Vv, tb)                                                            \
    do {                                                                       \
        _Pragma("unroll") for (int ks = 0; ks < 4; ++ks) {                     \
            Vv##0[ks] = *(const bfrag_t*)(pB0 + ((((size_t)(tb) << 2) + ks) << 10)); \
            Vv##1[ks] = *(const bfrag_t*)(pB1 + ((((size_t)(tb) << 2) + ks) << 10)); \
        }                                                                      \
    } while (0)

#define MFMA8(ar, Uv, ks)                                                      \
    do {                                                                       \
        __builtin_amdgcn_s_setprio(1);                                         \
        _Pragma("unroll") for (int mi = 0; mi < 4; ++mi) {                     \
            acc[mi][0] = __builtin_amdgcn_mfma_f32_32x32x16_bf16(              \
                ar[mi], Uv##0[ks], acc[mi][0], 0, 0, 0);                       \
            acc[mi][1] = __builtin_amdgcn_mfma_f32_32x32x16_bf16(              \
                ar[mi], Uv##1[ks], acc[mi][1], 0, 0, 0);                       \
        }                                                                      \
        __builtin_amdgcn_s_setprio(0);                                         \
    } while (0)

    f32x16 acc[4][2];
#pragma unroll
    for (int m = 0; m < 4; ++m)
#pragma unroll
        for (int n = 0; n < 2; ++n)
#pragma unroll
            for (int r = 0; r < 16; ++r)
                acc[m][n][r] = 0.f;

    const int NT = K >> 6;          // BK=64 tiles; NT even, >= 4

    bfrag_t U0[4], U1[4], V0[4], V1[4], aP[4], aQ[4];

    // ---- prologue: A(0)->buf0, B(0)->U, A(1)->buf1 ----
    STAGE_A4(0, 0);
    LDB(U, 0);
    STAGE_A4(32768, 1);
    WAITVM(4);      // drains A(0)+B(0); leaves A(1)'s 4 in flight
    BAR();

#define TILE(tv, XO, Ucur, Vnxt)                                               \
    do {                                                                       \
        int t1_ = (tv) + 1; if (t1_ >= NT) t1_ -= NT;  /* wrapped: harmless */ \
        int t2_ = (tv) + 2; if (t2_ >= NT) t2_ -= NT;                          \
        _Pragma("unroll") for (int mi = 0; mi < 4; ++mi) aP[mi] = RDA(XO, mi, 0); \
        SB();                                                                  \
        LDB(Vnxt, t1_);     /* B(t+1) -> regs; drains by tile-end vmcnt */     \
        SB();                                                                  \
        _Pragma("unroll") for (int mi = 0; mi < 4; ++mi) aQ[mi] = RDA(XO, mi, 1); \
        SB(); WAITLGKM(4); SB();   /* grp0 done; grp1 drains under MFMA */     \
        MFMA8(aP, Ucur, 0);                                                    \
        _Pragma("unroll") for (int mi = 0; mi < 4; ++mi) aP[mi] = RDA(XO, mi, 2); \
        SB(); WAITLGKM(4); SB();                                               \
        MFMA8(aQ, Ucur, 1);                                                    \
        _Pragma("unroll") for (int mi = 0; mi < 4; ++mi) aQ[mi] = RDA(XO, mi, 3); \
        SB(); WAITLGKM(4); SB();                                               \
        MFMA8(aP, Ucur, 2);                                                    \
        WAITLGKM(0); SB();  /* all this wave's reads of X drained */           \
        BAR();              /* block-wide: X free for overwrite */             \
        STAGE_A4(XO, t2_);                                                     \
        MFMA8(aQ, Ucur, 3);                                                    \
        WAITVM(4);          /* drains A(t+1)+B(t+1); leaves A(t+2)'s 4 */      \
        BAR();              /* publish A(t+1) */                               \
    } while (0)

    for (int tt = 0; tt < NT; tt += 2) {
        TILE(tt,     0,     U, V);
        TILE(tt + 1, 32768, V, U);
    }

    WAITVM(0);      // drain pending LDS writes before wave retires

    // ---- epilogue: 32x32 C/D layout col=lane&31, row=(reg&3)+8*(reg>>2)+4*(lane>>5) ----
    float bv[2];
#pragma unroll
    for (int nn = 0; nn < 2; ++nn) bv[nn] = bias[bcol + (wc << 6) + nn * 32 + lr32];
#pragma unroll
    for (int mm = 0; mm < 4; ++mm) {
#pragma unroll
        for (int nn = 0; nn < 2; ++nn) {
            const int gc = bcol + (wc << 6) + nn * 32 + lr32;
#pragma unroll
            for (int reg = 0; reg < 16; ++reg) {
                const int row = (reg & 3) + 8 * (reg >> 2) + 4 * hi;
                C[(size_t)(brow + (wr << 7) + mm * 32 + row) * N + gc] = acc[mm][nn][reg] + bv[nn];
            }
        }
    }
    (void)M;
#undef STAGE_A4
#undef RDA
#undef LDB
#undef MFMA8
#undef TILE
}

// ---------------------------------------------------------------------------
// Fallback: fp32 tiled GEMM with on-the-fly dequant (any shape, slow).
// ---------------------------------------------------------------------------
__global__ void gemm_fallback_kernel(const float* __restrict__ X, const float* __restrict__ W,
                                     const float* __restrict__ bias, float* __restrict__ C,
                                     int M, int N, int K) {
    __shared__ float sX[16][17];
    __shared__ float sW[16][17];
    const int tx = threadIdx.x & 15;
    const int ty = threadIdx.x >> 4;
    const int row = blockIdx.y * 16 + ty;
    const int colBase = blockIdx.x * 16;
    const int col = colBase + tx;
    float acc = 0.f;
    for (int k0 = 0; k0 < K; k0 += 16) {
        sX[ty][tx] = (row < M && k0 + tx < K) ? X[(size_t)row * K + k0 + tx] : 0.f;
        const int wrow = colBase + ty;
        sW[ty][tx] = (wrow < N && k0 + tx < K) ? dequant(W[(size_t)wrow * K + k0 + tx]) : 0.f;
        __syncthreads();
#pragma unroll
        for (int kk = 0; kk < 16; ++kk)
            acc += sX[ty][kk] * sW[tx][kk];
        __syncthreads();
    }
    if (row < M && col < N)
        C[(size_t)row * N + col] = acc + bias[col];
}

extern "C" void kernel_launch(void* const* d_in, const int* in_sizes, int n_in,
                              void* d_out, int out_size, void* d_ws, size_t ws_size,
                              hipStream_t stream) {
    const float* x    = (const float*)d_in[0];
    const float* w    = (const float*)d_in[1];
    const float* bias = (const float*)d_in[2];
    float* out        = (float*)d_out;

    const int N = in_sizes[2];
    const int K = in_sizes[1] / N;
    const int M = in_sizes[0] / K;

    const size_t need = ((size_t)M * K + (size_t)N * K) * sizeof(unsigned short);
    const bool fast = (ws_size >= need) && (M % 256 == 0) && (N % 256 == 0) &&
                      (K % 256 == 0);

    if (fast) {
        unsigned short* xp = (unsigned short*)d_ws;
        unsigned short* wp = xp + (size_t)M * K;
        pack_kernel<false><<<dim3((M / 32) * (K / 256)), dim3(256), 0, stream>>>(x, xp, K);
        pack_kernel<true ><<<dim3((N / 32) * (K / 256)), dim3(256), 0, stream>>>(w, wp, K);
        gemm256r_kernel<<<dim3((M / 256) * (N / 256)), dim3(512), 0, stream>>>(xp, wp, bias, out, M, N, K);
    } else {
        dim3 g((N + 15) / 16, (M + 15) / 16);
        gemm_fallback_kernel<<<g, dim3(256), 0, stream>>>(x, w, bias, out, M, N, K);
    }
    (void)n_in; (void)out_size;
}